// Round 1
// baseline (804.844 us; speedup 1.0000x reference)
//
#include <hip/hip_runtime.h>
#include <math.h>

// Problem constants (from reference)
#define N        8192
#define C        128
#define E_TOTAL  262144
#define WPR      256          // bitmap words per row = N/32
#define INV_TEMP 2.0f         // 1/0.5
#define STEPS    10

// ---- workspace layout (bytes) ----
// [0,16)              : float acc[4]  (acc[0]=sum log_sigmoid(pos), acc[1]=sum log_sigmoid(-neg))
// [1024, 1024+8MB)    : adjacency bitmap, N rows x 256 uint32
// then d_inv_sqrt[N], bufA[N*C], bufB[N*C]
#define OFF_ACC     0
#define OFF_BITMAP  1024
#define BITMAP_BYTES (N * WPR * 4)
#define OFF_D       (OFF_BITMAP + BITMAP_BYTES)
#define OFF_BUFA    (OFF_D + N * 4)
#define OFF_BUFB    (OFF_BUFA + N * C * 4)

__global__ void scatter_edges_kernel(const int* __restrict__ ei,
                                     unsigned int* __restrict__ bm) {
    int e = blockIdx.x * blockDim.x + threadIdx.x;
    if (e >= E_TOTAL) return;
    int s = ei[e];
    int t = ei[E_TOTAL + e];
    atomicOr(&bm[s * WPR + (t >> 5)], 1u << (t & 31));
}

__global__ void degree_kernel(const unsigned int* __restrict__ bm,
                              float* __restrict__ dinv) {
    int row = blockIdx.x;
    int lane = threadIdx.x;  // 64 threads = 1 wave
    const unsigned int* p = bm + row * WPR;
    int cnt = 0;
    for (int w = lane; w < WPR; w += 64) cnt += __popc(p[w]);
    for (int off = 32; off > 0; off >>= 1) cnt += __shfl_down(cnt, off, 64);
    if (lane == 0) dinv[row] = 1.0f / sqrtf((float)cnt);
}

// y[row, c] = dinv[row] * sum_{j in adj(row)} dinv[j] * x[j, c]
__global__ void spmm_kernel(const unsigned int* __restrict__ bm,
                            const float* __restrict__ dinv,
                            const float* __restrict__ x,
                            float* __restrict__ y) {
    __shared__ unsigned int words[WPR];
    int row = blockIdx.x;
    int c = threadIdx.x;  // 128 threads, one channel each
    const unsigned int* p = bm + row * WPR;
    words[c] = p[c];
    words[c + 128] = p[c + 128];
    __syncthreads();
    float acc = 0.0f;
    for (int w = 0; w < WPR; ++w) {
        unsigned int word = words[w];           // wave-uniform
        while (word) {                          // wave-uniform loop
            int b = __ffs(word) - 1;
            word &= word - 1;
            int j = (w << 5) + b;
            acc += dinv[j] * x[j * C + c];      // coalesced 512B row read
        }
    }
    y[row * C + c] = dinv[row] * acc;
}

__device__ __forceinline__ float log_sigmoid(float z) {
    // stable: min(z,0) - log1p(exp(-|z|))
    return fminf(z, 0.0f) - log1pf(expf(-fabsf(z)));
}

// sum over edges of log_sigmoid(dot(emb[s], emb[t]) / T) -> acc[0]
__global__ void pos_loss_kernel(const float* __restrict__ emb,
                                const int* __restrict__ ei,
                                float* __restrict__ acc) {
    int gtid = blockIdx.x * blockDim.x + threadIdx.x;
    int wave = gtid >> 6;
    int lane = threadIdx.x & 63;
    int nwaves = (gridDim.x * blockDim.x) >> 6;
    float sum = 0.0f;
    for (int e = wave; e < E_TOTAL; e += nwaves) {
        int s = ei[e];
        int t = ei[E_TOTAL + e];
        const float2* a = (const float2*)(emb + s * C);
        const float2* b = (const float2*)(emb + t * C);
        float2 av = a[lane];
        float2 bv = b[lane];
        float p = av.x * bv.x + av.y * bv.y;
        for (int off = 32; off > 0; off >>= 1) p += __shfl_down(p, off, 64);
        if (lane == 0) sum += log_sigmoid(p * INV_TEMP);
    }
    if (lane == 0) atomicAdd(&acc[0], sum);
}

// sum over rows of log_sigmoid(-dot(emb[i], emb[rand[i]]) / T) -> acc[1]
__global__ void neg_loss_kernel(const float* __restrict__ emb,
                                const int* __restrict__ ridx,
                                float* __restrict__ acc) {
    int gtid = blockIdx.x * blockDim.x + threadIdx.x;
    int wave = gtid >> 6;
    int lane = threadIdx.x & 63;
    int nwaves = (gridDim.x * blockDim.x) >> 6;
    float sum = 0.0f;
    for (int i = wave; i < N; i += nwaves) {
        int t = ridx[i];
        const float2* a = (const float2*)(emb + i * C);
        const float2* b = (const float2*)(emb + t * C);
        float2 av = a[lane];
        float2 bv = b[lane];
        float p = av.x * bv.x + av.y * bv.y;
        for (int off = 32; off > 0; off >>= 1) p += __shfl_down(p, off, 64);
        if (lane == 0) sum += log_sigmoid(-p * INV_TEMP);
    }
    if (lane == 0) atomicAdd(&acc[1], sum);
}

__global__ void finalize_kernel(const float* __restrict__ acc,
                                float* __restrict__ out) {
    out[0] = -(acc[0] / (float)E_TOTAL) - (acc[1] / (float)N);
}

extern "C" void kernel_launch(void* const* d_in, const int* in_sizes, int n_in,
                              void* d_out, int out_size, void* d_ws, size_t ws_size,
                              hipStream_t stream) {
    (void)in_sizes; (void)n_in; (void)out_size; (void)ws_size;

    const float* emb_in = (const float*)d_in[0];
    const int*   ei     = (const int*)d_in[1];   // (2, E) flattened: src then dst
    const int*   ridx   = (const int*)d_in[2];
    float* out = (float*)d_out;

    char* ws = (char*)d_ws;
    float*        acc  = (float*)(ws + OFF_ACC);
    unsigned int* bm   = (unsigned int*)(ws + OFF_BITMAP);
    float*        dinv = (float*)(ws + OFF_D);
    float*        bufA = (float*)(ws + OFF_BUFA);
    float*        bufB = (float*)(ws + OFF_BUFB);
    float*        buf[2] = {bufA, bufB};

    // zero the bitmap and the loss accumulators (ws is poisoned 0xAA each call)
    hipMemsetAsync(bm, 0, BITMAP_BYTES, stream);
    hipMemsetAsync(acc, 0, 16, stream);

    // build set-adjacency bitmap (dedup matches .at[].set(1.0) semantics)
    scatter_edges_kernel<<<E_TOTAL / 256, 256, 0, stream>>>(ei, bm);

    // degrees -> d^-1/2
    degree_kernel<<<N, 64, 0, stream>>>(bm, dinv);

    // 10 diffusion steps, ping-pong buffers; step 0 reads the pristine input
    for (int s = 0; s < STEPS; ++s) {
        const float* xs = (s == 0) ? emb_in : buf[(s + 1) & 1];
        float* yd = buf[s & 1];
        spmm_kernel<<<N, 128, 0, stream>>>(bm, dinv, xs, yd);
    }
    const float* emb = buf[(STEPS + 1) & 1];  // final result after 10 steps

    pos_loss_kernel<<<1024, 256, 0, stream>>>(emb, ei, acc);
    neg_loss_kernel<<<128, 256, 0, stream>>>(emb, ridx, acc);
    finalize_kernel<<<1, 1, 0, stream>>>(acc, out);
}

// Round 2
// 342.031 us; speedup vs baseline: 2.3531x; 2.3531x over previous
//
#include <hip/hip_runtime.h>
#include <math.h>

// Problem constants (from reference)
#define N        8192
#define C        128
#define E_TOTAL  262144
#define WPR      256          // bitmap words per row = N/32
#define INV_TEMP 2.0f         // 1/0.5
#define STEPS    10
#define S_ELL    96           // max neighbors per row (Poisson(32) tail safe)

// ---- workspace layout (bytes) ----
#define OFF_ACC     0                                   // float acc[4]
#define OFF_D       1024                                // float dinv[N]        (32 KB)
#define OFF_CNT     (OFF_D + N * 4)                     // int   cnt[N]         (32 KB)
#define OFF_COL     (OFF_CNT + N * 4)                   // int   col[N*S_ELL]   (3 MB)
#define OFF_WGT     (OFF_COL + N * S_ELL * 4)           // float wgt[N*S_ELL]   (3 MB)
#define OFF_BITMAP  (OFF_WGT + N * S_ELL * 4)           // bitmap 8 MB (dead after build)
#define BITMAP_BYTES (N * WPR * 4)
#define OFF_BUFA    OFF_BITMAP                          // alias: bufs reuse bitmap region
#define OFF_BUFB    (OFF_BUFA + N * C * 4)

__global__ void scatter_edges_kernel(const int* __restrict__ ei,
                                     unsigned int* __restrict__ bm) {
    int e = blockIdx.x * blockDim.x + threadIdx.x;
    if (e >= E_TOTAL) return;
    int s = ei[e];
    int t = ei[E_TOTAL + e];
    atomicOr(&bm[s * WPR + (t >> 5)], 1u << (t & 31));
}

__global__ void degree_kernel(const unsigned int* __restrict__ bm,
                              float* __restrict__ dinv) {
    int row = blockIdx.x;
    int lane = threadIdx.x;  // 64 threads = 1 wave
    const unsigned int* p = bm + row * WPR;
    int cnt = 0;
    for (int w = lane; w < WPR; w += 64) cnt += __popc(p[w]);
    for (int off = 32; off > 0; off >>= 1) cnt += __shfl_down(cnt, off, 64);
    if (lane == 0) dinv[row] = 1.0f / sqrtf((float)cnt);
}

// One-time: bitmap -> ELL (cols + pre-folded weights dinv[i]*dinv[j])
__global__ void build_ell_kernel(const unsigned int* __restrict__ bm,
                                 const float* __restrict__ dinv,
                                 int* __restrict__ cnt,
                                 int* __restrict__ col,
                                 float* __restrict__ wgt) {
    int row = blockIdx.x;
    int lane = threadIdx.x;  // 64 = one wave; each lane owns 4 consecutive words
    const unsigned int* p = bm + row * WPR;
    unsigned int w[4];
    int c = 0;
    for (int i = 0; i < 4; ++i) { w[i] = p[lane * 4 + i]; c += __popc(w[i]); }
    // inclusive scan of per-lane counts
    int inc = c;
    for (int off = 1; off < 64; off <<= 1) {
        int v = __shfl_up(inc, off, 64);
        if (lane >= off) inc += v;
    }
    int pos = inc - c;                       // exclusive offset
    int total = __shfl(inc, 63, 64);
    float dr = dinv[row];
    for (int i = 0; i < 4; ++i) {
        unsigned int word = w[i];
        int jbase = (lane * 4 + i) << 5;
        while (word) {
            int b = __ffs(word) - 1;
            word &= word - 1;
            int j = jbase + b;
            if (pos < S_ELL) {
                col[row * S_ELL + pos] = j;
                wgt[row * S_ELL + pos] = dr * dinv[j];
            }
            ++pos;
        }
    }
    if (lane == 0) cnt[row] = (total < S_ELL) ? total : S_ELL;
}

// y[row, c] = sum_k wgt[row,k] * x[col[row,k], c]   (weights pre-folded)
__global__ void spmm_ell_kernel(const int* __restrict__ cnt,
                                const int* __restrict__ col,
                                const float* __restrict__ wgt,
                                const float* __restrict__ x,
                                float* __restrict__ y) {
    __shared__ int   scol[S_ELL];
    __shared__ float swgt[S_ELL];
    int row = blockIdx.x;
    int c = threadIdx.x;  // 128 threads, one channel each
    int n = cnt[row];
    if (c < n) {                          // n <= 96 < 128: one pass
        scol[c] = col[row * S_ELL + c];
        swgt[c] = wgt[row * S_ELL + c];
    }
    __syncthreads();
    float a0 = 0.f, a1 = 0.f, a2 = 0.f, a3 = 0.f;
    int k = 0;
    for (; k + 4 <= n; k += 4) {
        int   j0 = scol[k],     j1 = scol[k + 1], j2 = scol[k + 2], j3 = scol[k + 3];
        float w0 = swgt[k],     w1 = swgt[k + 1], w2 = swgt[k + 2], w3 = swgt[k + 3];
        a0 += w0 * x[j0 * C + c];
        a1 += w1 * x[j1 * C + c];
        a2 += w2 * x[j2 * C + c];
        a3 += w3 * x[j3 * C + c];
    }
    for (; k < n; ++k) a0 += swgt[k] * x[scol[k] * C + c];
    y[row * C + c] = (a0 + a1) + (a2 + a3);
}

__device__ __forceinline__ float log_sigmoid(float z) {
    return fminf(z, 0.0f) - log1pf(expf(-fabsf(z)));
}

// 2 edges per wave per iteration: 32-lane halves, float4 loads
__global__ void pos_loss_kernel(const float* __restrict__ emb,
                                const int* __restrict__ ei,
                                float* __restrict__ acc) {
    int gtid = blockIdx.x * blockDim.x + threadIdx.x;
    int wave = gtid >> 6;
    int lane = threadIdx.x & 63;
    int half = lane >> 5;
    int lane32 = lane & 31;
    int nwaves = (gridDim.x * blockDim.x) >> 6;
    float sum = 0.0f;
    for (int base = wave * 2; base < E_TOTAL; base += nwaves * 2) {
        int e = base + half;
        int s = ei[e];
        int t = ei[E_TOTAL + e];
        const float4* a = (const float4*)(emb + s * C);
        const float4* b = (const float4*)(emb + t * C);
        float4 av = a[lane32];
        float4 bv = b[lane32];
        float p = av.x * bv.x + av.y * bv.y + av.z * bv.z + av.w * bv.w;
        p += __shfl_xor(p, 16, 64);
        p += __shfl_xor(p, 8, 64);
        p += __shfl_xor(p, 4, 64);
        p += __shfl_xor(p, 2, 64);
        p += __shfl_xor(p, 1, 64);
        if (lane32 == 0) sum += log_sigmoid(p * INV_TEMP);
    }
    sum += __shfl_xor(sum, 32, 64);  // lane 0 += lane 32's half
    if (lane == 0) atomicAdd(&acc[0], sum);
}

__global__ void neg_loss_kernel(const float* __restrict__ emb,
                                const int* __restrict__ ridx,
                                float* __restrict__ acc) {
    int gtid = blockIdx.x * blockDim.x + threadIdx.x;
    int wave = gtid >> 6;
    int lane = threadIdx.x & 63;
    int half = lane >> 5;
    int lane32 = lane & 31;
    int nwaves = (gridDim.x * blockDim.x) >> 6;
    float sum = 0.0f;
    for (int base = wave * 2; base < N; base += nwaves * 2) {
        int i = base + half;
        int t = ridx[i];
        const float4* a = (const float4*)(emb + i * C);
        const float4* b = (const float4*)(emb + t * C);
        float4 av = a[lane32];
        float4 bv = b[lane32];
        float p = av.x * bv.x + av.y * bv.y + av.z * bv.z + av.w * bv.w;
        p += __shfl_xor(p, 16, 64);
        p += __shfl_xor(p, 8, 64);
        p += __shfl_xor(p, 4, 64);
        p += __shfl_xor(p, 2, 64);
        p += __shfl_xor(p, 1, 64);
        if (lane32 == 0) sum += log_sigmoid(-p * INV_TEMP);
    }
    sum += __shfl_xor(sum, 32, 64);
    if (lane == 0) atomicAdd(&acc[1], sum);
}

__global__ void finalize_kernel(const float* __restrict__ acc,
                                float* __restrict__ out) {
    out[0] = -(acc[0] / (float)E_TOTAL) - (acc[1] / (float)N);
}

extern "C" void kernel_launch(void* const* d_in, const int* in_sizes, int n_in,
                              void* d_out, int out_size, void* d_ws, size_t ws_size,
                              hipStream_t stream) {
    (void)in_sizes; (void)n_in; (void)out_size; (void)ws_size;

    const float* emb_in = (const float*)d_in[0];
    const int*   ei     = (const int*)d_in[1];   // (2, E) flattened: src then dst
    const int*   ridx   = (const int*)d_in[2];
    float* out = (float*)d_out;

    char* ws = (char*)d_ws;
    float*        acc  = (float*)(ws + OFF_ACC);
    float*        dinv = (float*)(ws + OFF_D);
    int*          cnt  = (int*)(ws + OFF_CNT);
    int*          col  = (int*)(ws + OFF_COL);
    float*        wgt  = (float*)(ws + OFF_WGT);
    unsigned int* bm   = (unsigned int*)(ws + OFF_BITMAP);
    float*        bufA = (float*)(ws + OFF_BUFA);  // aliases bitmap (dead after build)
    float*        bufB = (float*)(ws + OFF_BUFB);
    float*        buf[2] = {bufA, bufB};

    hipMemsetAsync(bm, 0, BITMAP_BYTES, stream);
    hipMemsetAsync(acc, 0, 16, stream);

    // one-time sparse structure build
    scatter_edges_kernel<<<E_TOTAL / 256, 256, 0, stream>>>(ei, bm);
    degree_kernel<<<N, 64, 0, stream>>>(bm, dinv);
    build_ell_kernel<<<N, 64, 0, stream>>>(bm, dinv, cnt, col, wgt);

    // 10 diffusion steps, ping-pong buffers; step 0 reads the pristine input
    for (int s = 0; s < STEPS; ++s) {
        const float* xs = (s == 0) ? emb_in : buf[(s + 1) & 1];
        float* yd = buf[s & 1];
        spmm_ell_kernel<<<N, 128, 0, stream>>>(cnt, col, wgt, xs, yd);
    }
    const float* emb = buf[(STEPS + 1) & 1];

    pos_loss_kernel<<<2048, 256, 0, stream>>>(emb, ei, acc);
    neg_loss_kernel<<<256, 256, 0, stream>>>(emb, ridx, acc);
    finalize_kernel<<<1, 1, 0, stream>>>(acc, out);
}